// Round 1
// baseline (512.386 us; speedup 1.0000x reference)
//
#include <hip/hip_runtime.h>
#include <hip/hip_bf16.h>

#define B_  2
#define D_  256
#define H_  8
#define T_  128
#define S_  128
#define F_  64
#define C_  512
#define TE_ 512

typedef _Float16 f16x8 __attribute__((ext_vector_type(8)));
typedef _Float16 f16x4 __attribute__((ext_vector_type(4)));
typedef float    f32x4 __attribute__((ext_vector_type(4)));

#define AS1 __attribute__((address_space(1)))
#define AS3 __attribute__((address_space(3)))

// ---------------------------------------------------------------------------
// K1: tp[row][c] = temb[row,:] @ w_time[:,c] + b_time[c] + b_dist[c]
// 256 blocks (1 row each) x 128 threads, float4 w_time loads, dual accum.
// ---------------------------------------------------------------------------
__global__ __launch_bounds__(128) void k_time_proj(
    const float* __restrict__ temb, const float* __restrict__ w_time,
    const float* __restrict__ b_time, const float* __restrict__ b_dist,
    float* __restrict__ tp)
{
    int row = blockIdx.x;            // b*T + t
    int tid = threadIdx.x;
    __shared__ float te[TE_];
    for (int i = tid; i < TE_; i += 128)
        te[i] = temb[(size_t)row * TE_ + i];
    __syncthreads();
    int c0 = tid * 4;
    float4 b0 = *(const float4*)&b_time[c0];
    float4 b1 = *(const float4*)&b_dist[c0];
    float ax0 = 0.f, ay0 = 0.f, az0 = 0.f, aw0 = 0.f;
    float ax1 = 0.f, ay1 = 0.f, az1 = 0.f, aw1 = 0.f;
#pragma unroll 4
    for (int e = 0; e < TE_; e += 2) {
        float s0 = te[e], s1 = te[e + 1];
        float4 w0 = *(const float4*)&w_time[(size_t)e * C_ + c0];
        float4 w1 = *(const float4*)&w_time[(size_t)(e + 1) * C_ + c0];
        ax0 += s0 * w0.x; ay0 += s0 * w0.y; az0 += s0 * w0.z; aw0 += s0 * w0.w;
        ax1 += s1 * w1.x; ay1 += s1 * w1.y; az1 += s1 * w1.z; aw1 += s1 * w1.w;
    }
    float4 r;
    r.x = b0.x + b1.x + ax0 + ax1;
    r.y = b0.y + b1.y + ay0 + ay1;
    r.z = b0.z + b1.z + az0 + az1;
    r.w = b0.w + b1.w + aw0 + aw1;
    *(float4*)&tp[(size_t)row * C_ + c0] = r;
}

// ---------------------------------------------------------------------------
// K2: A[row][c] = f16( silu( tp[bt][c] + f0*wd0[c] + f1*wd1[c] + f2*wd2[c] ) )
// ---------------------------------------------------------------------------
__global__ __launch_bounds__(128) void k_embed_silu(
    const float* __restrict__ tp, const int* __restrict__ pd,
    const float* __restrict__ w_dist, _Float16* __restrict__ A)
{
    int row = blockIdx.x;
    int bt  = row >> 7;            // row / S_
    int d   = pd[row];
    float f0 = log1pf(fmaxf((float)d, 0.f));
    float f1 = log1pf(fmaxf((float)(-d), 0.f));
    float f2 = (d == 0) ? 1.f : 0.f;
    int c0 = threadIdx.x * 4;
    float4 t4 = *(const float4*)&tp[(size_t)bt * C_ + c0];
    float4 w0 = *(const float4*)&w_dist[c0];
    float4 w1 = *(const float4*)&w_dist[C_ + c0];
    float4 w2 = *(const float4*)&w_dist[2 * C_ + c0];
    float e0 = t4.x + f0 * w0.x + f1 * w1.x + f2 * w2.x;
    float e1 = t4.y + f0 * w0.y + f1 * w1.y + f2 * w2.y;
    float e2 = t4.z + f0 * w0.z + f1 * w1.z + f2 * w2.z;
    float e3 = t4.w + f0 * w0.w + f1 * w1.w + f2 * w2.w;
    f16x4 v;
    v.x = (_Float16)(e0 / (1.f + expf(-e0)));
    v.y = (_Float16)(e1 / (1.f + expf(-e1)));
    v.z = (_Float16)(e2 / (1.f + expf(-e2)));
    v.w = (_Float16)(e3 / (1.f + expf(-e3)));
    *(f16x4*)&A[(size_t)row * C_ + c0] = v;
}

// ---------------------------------------------------------------------------
// K2b: Wt[n][k] = f16(w_out[k][n])   (512 x 512)
// ---------------------------------------------------------------------------
__global__ __launch_bounds__(512) void k_wt(
    const float* __restrict__ w_out, _Float16* __restrict__ Wt)
{
    int n = blockIdx.x;
    int k = threadIdx.x;
    Wt[(size_t)n * C_ + k] = (_Float16)w_out[(size_t)k * C_ + n];
}

// ---------------------------------------------------------------------------
// K3: R = A(32768x512) @ Wt^T(512x512) + b_out   -> f16
// m97 structure: 128x128 tile, BK=64, linear LDS [128][64],
// global_load_lds width-16 staging, 256 threads (2x2 waves), 16x16x32 MFMA.
// ---------------------------------------------------------------------------
__global__ __launch_bounds__(256) void k_gemm_R(
    const _Float16* __restrict__ A, const _Float16* __restrict__ Wt,
    const float* __restrict__ b_out, _Float16* __restrict__ R)
{
    const int K = 512, N = 512;
    __shared__ _Float16 As[128][64];   // linear: global_load_lds needs contiguous dest
    __shared__ _Float16 Bs[128][64];
    int bm = blockIdx.x, bn = blockIdx.y;
    int tid = threadIdx.x;
    int wave = tid >> 6, lane = tid & 63;
    int wm = (wave >> 1) * 64, wn = (wave & 1) * 64;
    int mrow = lane & 15, kq = (lane >> 4) * 8;
    // per-lane source position inside the 8-row / 1KB chunk one gll instr fills:
    int grow = lane >> 3;          // 0..7  (row within chunk)
    int gcol = (lane & 7) * 8;     // f16 col (16B per lane)
    const size_t arow0 = (size_t)bm * 128;
    const size_t brow0 = (size_t)bn * 128;
    f32x4 acc[4][4] = {};
    for (int k0 = 0; k0 < K; k0 += 64) {
#pragma unroll
        for (int p = 0; p < 4; ++p) {
            int rb = (p * 4 + wave) * 8;   // wave-uniform chunk base row
            __builtin_amdgcn_global_load_lds(
                (const AS1 void*)(const void*)&A[(arow0 + rb + grow) * K + k0 + gcol],
                (AS3 void*)(void*)&As[rb][0], 16, 0, 0);
            __builtin_amdgcn_global_load_lds(
                (const AS1 void*)(const void*)&Wt[(brow0 + rb + grow) * K + k0 + gcol],
                (AS3 void*)(void*)&Bs[rb][0], 16, 0, 0);
        }
        __syncthreads();
#pragma unroll
        for (int ks = 0; ks < 64; ks += 32) {
            f16x8 af[4], bfr[4];
#pragma unroll
            for (int i = 0; i < 4; ++i) af[i]  = *(const f16x8*)&As[wm + i * 16 + mrow][ks + kq];
#pragma unroll
            for (int j = 0; j < 4; ++j) bfr[j] = *(const f16x8*)&Bs[wn + j * 16 + mrow][ks + kq];
#pragma unroll
            for (int i = 0; i < 4; ++i)
#pragma unroll
                for (int j = 0; j < 4; ++j)
                    acc[i][j] = __builtin_amdgcn_mfma_f32_16x16x32_f16(af[i], bfr[j], acc[i][j], 0, 0, 0);
        }
        __syncthreads();
    }
    // C/D layout (verified m89/m91): col = lane&15, row = (lane>>4)*4 + reg
    int col = lane & 15, rb = (lane >> 4) * 4;
#pragma unroll
    for (int j = 0; j < 4; ++j) {
        int n = bn * 128 + wn + j * 16 + col;
        float bo = b_out[n];
#pragma unroll
        for (int i = 0; i < 4; ++i)
#pragma unroll
            for (int r = 0; r < 4; ++r) {
                size_t m = arow0 + wm + i * 16 + rb + r;
                R[m * N + n] = (_Float16)(acc[i][j][r] + bo);
            }
    }
}

// ---------------------------------------------------------------------------
// K4: out[b,d,h,t,s] = sum_f qk[b,d,h,t,f] * R[(b*T+t)*S+s][h*64+f]
// LDS-free: fragments straight global->VGPR (A-frag elements have no
// cross-wave reuse, so LDS round-trip + 2 barrier drains bought nothing).
// Operand-swapped MFMA: acc[j][i] = mfma(R_frag, qk_frag) puts the s index
// (contiguous output dim) on the register axis -> f32x4 stores (1KB/instr).
// ---------------------------------------------------------------------------
__global__ __launch_bounds__(256) void k_einsum(
    const float* __restrict__ qk, const _Float16* __restrict__ R,
    float* __restrict__ out)
{
    int bht  = blockIdx.x;          // b*H*T + h*T + t
    int dblk = blockIdx.y;          // 0 / 1
    int t = bht & 127;
    int h = (bht >> 7) & 7;
    int b = bht >> 10;
    int tid = threadIdx.x;
    int wave = tid >> 6, lane = tid & 63;
    int wm = (wave >> 1) * 64, wn = (wave & 1) * 64;
    int mrow = lane & 15, kq = (lane >> 4) * 8;

    const size_t qstr  = (size_t)(H_ * T_ * F_);
    const size_t qbase = (size_t)b * (D_ * H_ * T_ * F_) + (size_t)h * (T_ * F_)
                       + (size_t)t * F_ + (size_t)dblk * 128 * qstr;
    const size_t rbase = ((size_t)(b * T_ + t) * S_) * C_ + h * 64;

    f32x4 acc[4][4] = {};           // [j: s-tile][i: d-tile]
#pragma unroll
    for (int ks = 0; ks < 64; ks += 32) {
        f16x8 bf[4], aq[4];
#pragma unroll
        for (int j = 0; j < 4; ++j)
            bf[j] = *(const f16x8*)&R[rbase + (size_t)(wn + j * 16 + mrow) * C_ + ks + kq];
#pragma unroll
        for (int i = 0; i < 4; ++i) {
            const float* qp = &qk[qbase + (size_t)(wm + i * 16 + mrow) * qstr + ks + kq];
            float4 u = *(const float4*)qp;
            float4 v = *(const float4*)(qp + 4);
            f16x8 a;
            a[0] = (_Float16)u.x; a[1] = (_Float16)u.y;
            a[2] = (_Float16)u.z; a[3] = (_Float16)u.w;
            a[4] = (_Float16)v.x; a[5] = (_Float16)v.y;
            a[6] = (_Float16)v.z; a[7] = (_Float16)v.w;
            aq[i] = a;
        }
#pragma unroll
        for (int j = 0; j < 4; ++j)
#pragma unroll
            for (int i = 0; i < 4; ++i)
                acc[j][i] = __builtin_amdgcn_mfma_f32_16x16x32_f16(bf[j], aq[i], acc[j][i], 0, 0, 0);
    }

    // transposed D layout: col = lane&15 -> d offset, (lane>>4)*4+reg -> s offset
    const size_t ostr  = (size_t)(H_ * T_ * S_);
    const size_t obase = (size_t)b * (D_ * H_ * T_ * S_) + (size_t)h * (T_ * S_)
                       + (size_t)t * S_ + (size_t)dblk * 128 * ostr;
    int dcol = lane & 15, sb = (lane >> 4) * 4;
#pragma unroll
    for (int i = 0; i < 4; ++i) {
        size_t orow = obase + (size_t)(wm + i * 16 + dcol) * ostr + wn + sb;
#pragma unroll
        for (int j = 0; j < 4; ++j)
            *(f32x4*)&out[orow + j * 16] = acc[j][i];
    }
}

// ---------------------------------------------------------------------------
extern "C" void kernel_launch(void* const* d_in, const int* in_sizes, int n_in,
                              void* d_out, int out_size, void* d_ws, size_t ws_size,
                              hipStream_t stream) {
    (void)in_sizes; (void)n_in; (void)out_size; (void)ws_size;
    const float* qk     = (const float*)d_in[0];
    const float* temb   = (const float*)d_in[1];
    const int*   pd     = (const int*)d_in[2];
    const float* w_dist = (const float*)d_in[3];
    const float* b_dist = (const float*)d_in[4];
    const float* w_time = (const float*)d_in[5];
    const float* b_time = (const float*)d_in[6];
    const float* w_out  = (const float*)d_in[7];
    const float* b_out  = (const float*)d_in[8];
    float* out = (float*)d_out;

    char* ws = (char*)d_ws;
    float*     tp = (float*)ws;                                  // 512 KB
    _Float16*  Wt = (_Float16*)(ws + 512 * 1024);                // 512 KB
    _Float16*  A  = (_Float16*)(ws + 1024 * 1024);               // 32 MB
    _Float16*  R  = (_Float16*)(ws + 1024 * 1024 + 33554432);    // 32 MB

    k_time_proj<<<dim3(B_ * T_), dim3(128), 0, stream>>>(temb, w_time, b_time, b_dist, tp);
    k_wt<<<dim3(C_), dim3(C_), 0, stream>>>(w_out, Wt);
    k_embed_silu<<<dim3(B_ * T_ * S_), dim3(128), 0, stream>>>(tp, pd, w_dist, A);
    k_gemm_R<<<dim3(256, 4), dim3(256), 0, stream>>>(A, Wt, b_out, R);
    k_einsum<<<dim3(B_ * H_ * T_, 2), dim3(256), 0, stream>>>(qk, R, out);
}